// Round 2
// baseline (270.117 us; speedup 1.0000x reference)
//
#include <hip/hip_runtime.h>
#include <hip/hip_bf16.h>
#include <math.h>

#define B_DIM 16
#define T_DIM 4096
#define D_DIM 512
#define R_DIM 256

#define TM 128          // rows (t) per block
#define BK 64           // k-tile (2 MFMA k-steps of 32)
#define LDP 72          // LDS row pitch in bf16 (144 B): uniform bank spread, 2-way max
#define NKS (D_DIM/32)  // 16 k-steps of 32 in fragment-ordered B layout

typedef __bf16 bf16x8 __attribute__((ext_vector_type(8)));
typedef float floatx4 __attribute__((ext_vector_type(4)));

// Replicate np.linspace(0, T-1, R).astype(int64) bit-exactly.
__device__ __forceinline__ int landmark_of(int r) {
    if (r >= 255) return 4095;
    const double step = 4095.0 / 255.0;
    return (int)((double)r * step);   // trunc toward zero == astype(int64)
}

__device__ __forceinline__ void split_bf16(float x, __bf16& h, __bf16& l) {
    h = (__bf16)x;
    l = (__bf16)(x - (float)h);
}

// ---- prep: normalized landmark rows of z, split hi/lo, written in MFMA
// FRAGMENT order: Kf[b][ks 0..15][rb 0..15][lam 0..63][8 bf16], where
// lam = col_octet*16 + (r&15) and element j is B[r = rb*16 + (r&15)][k =
// ks*32 + col_octet*8 + j]. Main kernel then loads B fragments directly
// from global (1 KB fully-coalesced per wave-load), no LDS round-trip. ----
__global__ void nystrom_prep_kernel(const float* __restrict__ z,
                                    __bf16* __restrict__ Khi, __bf16* __restrict__ Klo) {
    int blk = blockIdx.x;
    int b = blk >> 8;
    int r = blk & 255;
    int lane = threadIdx.x;            // 64 threads
    int lm = landmark_of(r);
    const float* src = z + ((size_t)b * T_DIM + lm) * D_DIM + lane * 8;
    float4 v0 = ((const float4*)src)[0];
    float4 v1 = ((const float4*)src)[1];
    float ss = v0.x*v0.x + v0.y*v0.y + v0.z*v0.z + v0.w*v0.w
             + v1.x*v1.x + v1.y*v1.y + v1.z*v1.z + v1.w*v1.w;
    #pragma unroll
    for (int off = 1; off < 64; off <<= 1) ss += __shfl_xor(ss, off, 64);
    float inv = 1.0f / fmaxf(sqrtf(ss), 1e-12f);
    float q[8] = {v0.x*inv, v0.y*inv, v0.z*inv, v0.w*inv,
                  v1.x*inv, v1.y*inv, v1.z*inv, v1.w*inv};
    bf16x8 oh, ol;
    #pragma unroll
    for (int j = 0; j < 8; j++) { __bf16 h, l; split_bf16(q[j], h, l); oh[j] = h; ol[j] = l; }
    // this thread's 8 cols: ks = lane>>2 (32-col step), col_octet = lane&3
    size_t dst = ((((size_t)b * NKS + (lane >> 2)) * 16 + (r >> 4)) * 64
                  + (size_t)(lane & 3) * 16 + (r & 15)) * 8;
    *(bf16x8*)(Khi + dst) = oh;
    *(bf16x8*)(Klo + dst) = ol;
}

// ---- main: split-bf16 GEMM (z @ Kn^T) + norm + polynomial + mask/decay + row-normalize.
// A (z tile) staged in LDS (4x wave reuse); B read as fragments straight from
// global (L2-hot, zero LDS reuse anyway). Register-bound at 2 waves/SIMD
// (acc = 128 AGPR on the unified file), so __launch_bounds__(256,2) — forcing
// more waves would spill the accumulator. ----
__global__ __launch_bounds__(256, 2)
void nystrom_main_kernel(const float* __restrict__ z,
                         const __bf16* __restrict__ Khi, const __bf16* __restrict__ Klo,
                         const float* __restrict__ gw, const float* __restrict__ ta,
                         float* __restrict__ out) {
    // A-tile buffers (K-loop) aliased with epilogue scratch (strictly after last barrier).
    __shared__ __attribute__((aligned(16))) char smem[36864];
    __shared__ int   lmtab[R_DIM];
    __shared__ float elmtab[R_DIM];

    __bf16* Ash = (__bf16*)(smem);            // 128*72*2 = 18432 B
    __bf16* Asl = (__bf16*)(smem + 18432);    // 18432 B
    float* red    = (float*)(smem);           // 1024 B   (epilogue alias)
    float* rnormp = (float*)(smem + 1024);    // 512 B
    float* rinvp  = (float*)(smem + 1536);    // 512 B
    float* rspart = (float*)(smem + 2048);    // 4*128*4 = 2048 B

    const int tid  = threadIdx.x;
    const int b    = blockIdx.y;
    const int t0   = blockIdx.x * TM;
    const int lane = tid & 63;
    const int wv   = tid >> 6;
    const int quad = lane >> 4;
    const int ln   = lane & 15;

    // --- scalars (recomputed per thread; trivial) ---
    float g0 = gw[0], g1 = gw[1], g2 = gw[2];
    float gm = fmaxf(g0, fmaxf(g1, g2));
    float e0 = expf(g0 - gm), e1 = expf(g1 - gm), e2 = expf(g2 - gm);
    float esum = e0 + e1 + e2;
    float al0 = e0 / esum, al1 = e1 / esum, al2 = e2 / esum;
    float ax = ta[0];
    float a_td = (ax > 20.f) ? ax : log1pf(expf(ax));

    {
        int lm = landmark_of(tid);
        lmtab[tid] = lm;
        elmtab[tid] = expf(a_td * (float)lm * (1.0f / 4096.0f));
    }

    // staging map: A = 2 lanes per row (32 cols each of the 64-col tile)
    const int srowA = tid >> 1;
    const int scolA = (tid & 1) * 32;
    const float* zrow = z + ((size_t)b * T_DIM + (t0 + srowA)) * D_DIM + scolA;

    // B fragment base: elem offset = ((b*NKS + ks)*16 + rb)*64*8 + lane*8,
    // rb = wv*4 + ni  ->  per (ks,ni) offset = ks*8192 + ni*512
    const size_t kfoff = (size_t)b * (NKS * 16 * 64 * 8)
                       + (size_t)wv * 2048 + (size_t)lane * 8;
    const __bf16* khb = Khi + kfoff;
    const __bf16* klb = Klo + kfoff;

    floatx4 acc[8][4];
    #pragma unroll
    for (int i = 0; i < 8; i++)
        #pragma unroll
        for (int j = 0; j < 4; j++) acc[i][j] = (floatx4){0.f, 0.f, 0.f, 0.f};
    float ssq = 0.0f;

    // ---- prefetch A tile 0 into registers (32 floats = 128 B/thread) ----
    float4 a0, a1, a2, a3, a4, a5, a6, a7;
    {
        const float4* ap = (const float4*)(zrow);
        a0 = ap[0]; a1 = ap[1]; a2 = ap[2]; a3 = ap[3];
        a4 = ap[4]; a5 = ap[5]; a6 = ap[6]; a7 = ap[7];
    }

    #pragma unroll 1
    for (int kt = 0; kt < D_DIM; kt += BK) {
        // --- consume regs: convert A, accumulate ssq, write LDS ---
        float av[32] = {a0.x,a0.y,a0.z,a0.w, a1.x,a1.y,a1.z,a1.w,
                        a2.x,a2.y,a2.z,a2.w, a3.x,a3.y,a3.z,a3.w,
                        a4.x,a4.y,a4.z,a4.w, a5.x,a5.y,a5.z,a5.w,
                        a6.x,a6.y,a6.z,a6.w, a7.x,a7.y,a7.z,a7.w};
        #pragma unroll
        for (int j = 0; j < 32; j++) ssq += av[j] * av[j];
        #pragma unroll
        for (int g = 0; g < 4; g++) {
            bf16x8 ph, pl;
            #pragma unroll
            for (int j = 0; j < 8; j++) {
                __bf16 h, l; split_bf16(av[g*8+j], h, l); ph[j] = h; pl[j] = l;
            }
            *(bf16x8*)&Ash[srowA * LDP + scolA + g*8] = ph;
            *(bf16x8*)&Asl[srowA * LDP + scolA + g*8] = pl;
        }
        __syncthreads();

        // --- prefetch next A tile (in flight across the whole MFMA phase) ---
        if (kt + BK < D_DIM) {
            const float4* ap = (const float4*)(zrow + kt + BK);
            a0 = ap[0]; a1 = ap[1]; a2 = ap[2]; a3 = ap[3];
            a4 = ap[4]; a5 = ap[5]; a6 = ap[6]; a7 = ap[7];
        }

        // --- MFMA: two k-steps of 32; B fragments straight from global (L2-hot) ---
        const int ksb = kt >> 5;
        #pragma unroll
        for (int s = 0; s < 2; s++) {
            const __bf16* khp = khb + (size_t)(ksb + s) * 8192;
            const __bf16* klp = klb + (size_t)(ksb + s) * 8192;
            bf16x8 bh[4], bl[4];
            #pragma unroll
            for (int ni = 0; ni < 4; ni++) {
                bh[ni] = *(const bf16x8*)(khp + ni * 512);
                bl[ni] = *(const bf16x8*)(klp + ni * 512);
            }
            const int koff = s * 32 + quad * 8;
            #pragma unroll
            for (int mi = 0; mi < 8; mi++) {
                bf16x8 afh = *(const bf16x8*)&Ash[(mi * 16 + ln) * LDP + koff];
                bf16x8 afl = *(const bf16x8*)&Asl[(mi * 16 + ln) * LDP + koff];
                #pragma unroll
                for (int ni = 0; ni < 4; ni++) {
                    acc[mi][ni] = __builtin_amdgcn_mfma_f32_16x16x32_bf16(
                        afh, bh[ni], acc[mi][ni], 0, 0, 0);
                    acc[mi][ni] = __builtin_amdgcn_mfma_f32_16x16x32_bf16(
                        afh, bl[ni], acc[mi][ni], 0, 0, 0);
                    acc[mi][ni] = __builtin_amdgcn_mfma_f32_16x16x32_bf16(
                        afl, bh[ni], acc[mi][ni], 0, 0, 0);
                }
            }
        }
        __syncthreads();
    }

    // --- row norms: 2 partials per row (epilogue scratch aliases tile LDS) ---
    red[tid] = ssq;
    __syncthreads();
    if (tid < TM) {
        float s = red[tid * 2] + red[tid * 2 + 1];
        rnormp[tid] = 1.0f / fmaxf(sqrtf(s), 1e-12f);
    }
    __syncthreads();

    // per-thread landmark columns
    int   lm_r[4];
    float elm_r[4];
    #pragma unroll
    for (int ni = 0; ni < 4; ni++) {
        int r = wv * 64 + ni * 16 + ln;
        lm_r[ni]  = lmtab[r];
        elm_r[ni] = elmtab[r];
    }

    // --- polynomial + mask + decay; row-sum reduce ---
    #pragma unroll
    for (int mi = 0; mi < 8; mi++) {
        #pragma unroll
        for (int reg = 0; reg < 4; reg++) {
            int row = mi * 16 + quad * 4 + reg;
            int t = t0 + row;
            float rn = rnormp[row];
            float e_t = expf(-a_td * (float)t * (1.0f / 4096.0f));
            float s = 0.f;
            #pragma unroll
            for (int ni = 0; ni < 4; ni++) {
                float phi = 0.f;
                if (lm_r[ni] < t) {
                    float c  = acc[mi][ni][reg] * rn;
                    float c2 = c * c;
                    float P1 = 0.5f * (1.f + c);
                    float P2 = 0.5f * (3.f * c2 - 1.f);
                    float P3 = 0.5f * (5.f * c2 * c - 3.f * c);
                    float p  = al0 * P1 + al1 * P2 + al2 * P3;
                    phi = p * e_t * elm_r[ni];
                }
                acc[mi][ni][reg] = phi;
                s += phi;
            }
            #pragma unroll
            for (int off = 1; off < 16; off <<= 1) s += __shfl_xor(s, off, 64);
            if (ln == 0) rspart[wv * TM + row] = s;
        }
    }
    __syncthreads();
    if (tid < TM) {
        float rs = rspart[0 * TM + tid] + rspart[1 * TM + tid]
                 + rspart[2 * TM + tid] + rspart[3 * TM + tid];
        rinvp[tid] = 1.0f / fmaxf(rs, 1e-6f);
    }
    __syncthreads();

    // --- store Phi + ones column ---
    float* ob = out + ((size_t)b * T_DIM + t0) * 257;
    #pragma unroll
    for (int mi = 0; mi < 8; mi++) {
        #pragma unroll
        for (int reg = 0; reg < 4; reg++) {
            int row = mi * 16 + quad * 4 + reg;
            float inv = rinvp[row];
            #pragma unroll
            for (int ni = 0; ni < 4; ni++) {
                int r = wv * 64 + ni * 16 + ln;
                ob[(size_t)row * 257 + r] = acc[mi][ni][reg] * inv;
            }
        }
    }
    if (tid < TM) ob[(size_t)tid * 257 + 256] = 1.0f;
}

extern "C" void kernel_launch(void* const* d_in, const int* in_sizes, int n_in,
                              void* d_out, int out_size, void* d_ws, size_t ws_size,
                              hipStream_t stream) {
    const float* z  = (const float*)d_in[0];
    const float* gw = (const float*)d_in[1];
    const float* ta = (const float*)d_in[2];
    float* out = (float*)d_out;
    __bf16* Khi = (__bf16*)d_ws;                                               // 4 MiB
    __bf16* Klo = (__bf16*)((char*)d_ws + (size_t)B_DIM * R_DIM * D_DIM * 2);  // +4 MiB

    nystrom_prep_kernel<<<dim3(B_DIM * R_DIM), 64, 0, stream>>>(z, Khi, Klo);
    nystrom_main_kernel<<<dim3(T_DIM / TM, B_DIM), 256, 0, stream>>>(z, Khi, Klo, gw, ta, out);
}

// Round 4
// 259.638 us; speedup vs baseline: 1.0404x; 1.0404x over previous
//
#include <hip/hip_runtime.h>
#include <hip/hip_bf16.h>
#include <math.h>

#define B_DIM 16
#define T_DIM 4096
#define D_DIM 512
#define R_DIM 256

#define TM 64           // rows (t) per block (acc 64 AGPR -> 3 waves/SIMD)
#define BK 64           // k-tile (2 MFMA k-steps of 32)
#define LDP 72          // LDS row pitch in bf16 (144 B): uniform bank spread
#define NKS (D_DIM/32)  // 16 k-steps of 32 in fragment-ordered B layout

typedef __bf16 bf16x8 __attribute__((ext_vector_type(8)));
typedef float floatx4 __attribute__((ext_vector_type(4)));

// Replicate np.linspace(0, T-1, R).astype(int64) bit-exactly.
__device__ __forceinline__ int landmark_of(int r) {
    if (r >= 255) return 4095;
    const double step = 4095.0 / 255.0;
    return (int)((double)r * step);   // trunc toward zero == astype(int64)
}

__device__ __forceinline__ void split_bf16(float x, __bf16& h, __bf16& l) {
    h = (__bf16)x;
    l = (__bf16)(x - (float)h);
}

// ---- prep: normalized landmark rows of z, split hi/lo, written in MFMA
// FRAGMENT order: Kf[b][ks 0..15][rb 0..15][lam 0..63][8 bf16], where
// lam = col_octet*16 + (r&15) and element j is B[r = rb*16 + (r&15)][k =
// ks*32 + col_octet*8 + j]. Main kernel loads B fragments directly from
// global (1 KB fully-coalesced per wave-load), no LDS round-trip. ----
__global__ void nystrom_prep_kernel(const float* __restrict__ z,
                                    __bf16* __restrict__ Khi, __bf16* __restrict__ Klo) {
    int blk = blockIdx.x;
    int b = blk >> 8;
    int r = blk & 255;
    int lane = threadIdx.x;            // 64 threads
    int lm = landmark_of(r);
    const float* src = z + ((size_t)b * T_DIM + lm) * D_DIM + lane * 8;
    float4 v0 = ((const float4*)src)[0];
    float4 v1 = ((const float4*)src)[1];
    float ss = v0.x*v0.x + v0.y*v0.y + v0.z*v0.z + v0.w*v0.w
             + v1.x*v1.x + v1.y*v1.y + v1.z*v1.z + v1.w*v1.w;
    #pragma unroll
    for (int off = 1; off < 64; off <<= 1) ss += __shfl_xor(ss, off, 64);
    float inv = 1.0f / fmaxf(sqrtf(ss), 1e-12f);
    float q[8] = {v0.x*inv, v0.y*inv, v0.z*inv, v0.w*inv,
                  v1.x*inv, v1.y*inv, v1.z*inv, v1.w*inv};
    bf16x8 oh, ol;
    #pragma unroll
    for (int j = 0; j < 8; j++) { __bf16 h, l; split_bf16(q[j], h, l); oh[j] = h; ol[j] = l; }
    // this thread's 8 cols: ks = lane>>2 (32-col step), col_octet = lane&3
    size_t dst = ((((size_t)b * NKS + (lane >> 2)) * 16 + (r >> 4)) * 64
                  + (size_t)(lane & 3) * 16 + (r & 15)) * 8;
    *(bf16x8*)(Khi + dst) = oh;
    *(bf16x8*)(Klo + dst) = ol;
}

// ---- main: split-bf16 GEMM (z @ Kn^T) + norm + polynomial + mask/decay +
// row-normalize. TM=64 tile: acc[4][4]=64 AGPR -> ~160 unified regs ->
// 3 waves/SIMD (12 waves/CU with 3 resident blocks). A double-buffered in
// LDS, ONE barrier per k-iter; B fragments straight from global (L2-hot). ----
__global__ __launch_bounds__(256, 3)
void nystrom_main_kernel(const float* __restrict__ z,
                         const __bf16* __restrict__ Khi, const __bf16* __restrict__ Klo,
                         const float* __restrict__ gw, const float* __restrict__ ta,
                         float* __restrict__ out) {
    // Double-buffered A tiles; epilogue scratch aliases buffer 0 (disjoint from
    // buffer 1, which the last iteration reads).
    __shared__ __attribute__((aligned(16))) char smem[36864];
    __shared__ int   lmtab[R_DIM];
    __shared__ float elmtab[R_DIM];
    // buf layout: buf c at smem + c*18432 (Ash), + c*18432 + 9216 (Asl)

    float* red    = (float*)(smem);           // 1024 B (epilogue alias, buf0)
    float* rnormp = (float*)(smem + 1024);    // 256 B
    float* rinvp  = (float*)(smem + 1280);    // 256 B
    float* rspart = (float*)(smem + 1536);    // 4*64*4 = 1024 B

    const int tid  = threadIdx.x;
    const int b    = blockIdx.y;
    const int t0   = blockIdx.x * TM;
    const int lane = tid & 63;
    const int wv   = tid >> 6;
    const int quad = lane >> 4;
    const int ln   = lane & 15;

    // --- scalars (recomputed per thread; trivial) ---
    float g0 = gw[0], g1 = gw[1], g2 = gw[2];
    float gm = fmaxf(g0, fmaxf(g1, g2));
    float e0 = expf(g0 - gm), e1 = expf(g1 - gm), e2 = expf(g2 - gm);
    float esum = e0 + e1 + e2;
    float al0 = e0 / esum, al1 = e1 / esum, al2 = e2 / esum;
    float ax = ta[0];
    float a_td = (ax > 20.f) ? ax : log1pf(expf(ax));

    {
        int lm = landmark_of(tid);
        lmtab[tid] = lm;
        elmtab[tid] = expf(a_td * (float)lm * (1.0f / 4096.0f));
    }

    // staging map: 4 lanes per row, 16 cols each (64x64 tile, 16 floats/thread)
    const int srowA = tid >> 2;
    const int scolA = (tid & 3) * 16;
    const float* zrow = z + ((size_t)b * T_DIM + (t0 + srowA)) * D_DIM + scolA;

    // B fragment base: elem offset = ((b*NKS + ks)*16 + rb)*512 + lane*8,
    // rb = wv*4 + ni  ->  per (ks,ni) offset = ks*8192 + ni*512
    const size_t kfoff = (size_t)b * (NKS * 16 * 64 * 8)
                       + (size_t)wv * 2048 + (size_t)lane * 8;
    const __bf16* khb = Khi + kfoff;
    const __bf16* klb = Klo + kfoff;

    floatx4 acc[4][4];
    #pragma unroll
    for (int i = 0; i < 4; i++)
        #pragma unroll
        for (int j = 0; j < 4; j++) acc[i][j] = (floatx4){0.f, 0.f, 0.f, 0.f};
    float ssq = 0.0f;

    float4 a0, a1, a2, a3;   // 16-float A prefetch (64 B/thread)

    // ---- prologue: load + convert + write tile 0 into buf0 ----
    {
        const float4* ap = (const float4*)(zrow);
        a0 = ap[0]; a1 = ap[1]; a2 = ap[2]; a3 = ap[3];
        float av[16] = {a0.x,a0.y,a0.z,a0.w, a1.x,a1.y,a1.z,a1.w,
                        a2.x,a2.y,a2.z,a2.w, a3.x,a3.y,a3.z,a3.w};
        #pragma unroll
        for (int j = 0; j < 16; j++) ssq += av[j] * av[j];
        __bf16* wsh = (__bf16*)(smem);
        __bf16* wsl = (__bf16*)(smem + 9216);
        #pragma unroll
        for (int g = 0; g < 2; g++) {
            bf16x8 ph, pl;
            #pragma unroll
            for (int j = 0; j < 8; j++) {
                __bf16 h, l; split_bf16(av[g*8+j], h, l); ph[j] = h; pl[j] = l;
            }
            *(bf16x8*)&wsh[srowA * LDP + scolA + g*8] = ph;
            *(bf16x8*)&wsl[srowA * LDP + scolA + g*8] = pl;
        }
    }
    __syncthreads();

    #pragma unroll 1
    for (int kt = 0; kt < D_DIM; kt += BK) {
        const int cur = (kt >> 6) & 1;
        const bool has_next = (kt + BK < D_DIM);

        // --- issue next A-tile global loads (in flight across MFMA phase) ---
        if (has_next) {
            const float4* ap = (const float4*)(zrow + kt + BK);
            a0 = ap[0]; a1 = ap[1]; a2 = ap[2]; a3 = ap[3];
        }

        // --- MFMA: two k-steps of 32; B fragments straight from global ---
        const __bf16* Ash = (const __bf16*)(smem + cur * 18432);
        const __bf16* Asl = (const __bf16*)(smem + cur * 18432 + 9216);
        const int ksb = kt >> 5;
        #pragma unroll
        for (int s = 0; s < 2; s++) {
            const __bf16* khp = khb + (size_t)(ksb + s) * 8192;
            const __bf16* klp = klb + (size_t)(ksb + s) * 8192;
            bf16x8 bh[4], bl[4];
            #pragma unroll
            for (int ni = 0; ni < 4; ni++) {
                bh[ni] = *(const bf16x8*)(khp + ni * 512);
                bl[ni] = *(const bf16x8*)(klp + ni * 512);
            }
            const int koff = s * 32 + quad * 8;
            #pragma unroll
            for (int mi = 0; mi < 4; mi++) {
                bf16x8 afh = *(const bf16x8*)&Ash[(mi * 16 + ln) * LDP + koff];
                bf16x8 afl = *(const bf16x8*)&Asl[(mi * 16 + ln) * LDP + koff];
                #pragma unroll
                for (int ni = 0; ni < 4; ni++) {
                    acc[mi][ni] = __builtin_amdgcn_mfma_f32_16x16x32_bf16(
                        afh, bh[ni], acc[mi][ni], 0, 0, 0);
                    acc[mi][ni] = __builtin_amdgcn_mfma_f32_16x16x32_bf16(
                        afh, bl[ni], acc[mi][ni], 0, 0, 0);
                    acc[mi][ni] = __builtin_amdgcn_mfma_f32_16x16x32_bf16(
                        afl, bh[ni], acc[mi][ni], 0, 0, 0);
                }
            }
        }

        // --- convert + write next tile into the other buffer ---
        if (has_next) {
            float av[16] = {a0.x,a0.y,a0.z,a0.w, a1.x,a1.y,a1.z,a1.w,
                            a2.x,a2.y,a2.z,a2.w, a3.x,a3.y,a3.z,a3.w};
            #pragma unroll
            for (int j = 0; j < 16; j++) ssq += av[j] * av[j];
            __bf16* wsh = (__bf16*)(smem + (cur ^ 1) * 18432);
            __bf16* wsl = (__bf16*)(smem + (cur ^ 1) * 18432 + 9216);
            #pragma unroll
            for (int g = 0; g < 2; g++) {
                bf16x8 ph, pl;
                #pragma unroll
                for (int j = 0; j < 8; j++) {
                    __bf16 h, l; split_bf16(av[g*8+j], h, l); ph[j] = h; pl[j] = l;
                }
                *(bf16x8*)&wsh[srowA * LDP + scolA + g*8] = ph;
                *(bf16x8*)&wsl[srowA * LDP + scolA + g*8] = pl;
            }
        }
        __syncthreads();   // single barrier per k-iter
    }

    // --- row norms: 4 partials per row (epilogue scratch aliases buf0; the
    // last MFMA iteration read buf1 -> disjoint, and the loop-end barrier
    // ordered all reads anyway) ---
    red[tid] = ssq;
    __syncthreads();
    if (tid < TM) {
        float s = red[tid * 4] + red[tid * 4 + 1] + red[tid * 4 + 2] + red[tid * 4 + 3];
        rnormp[tid] = 1.0f / fmaxf(sqrtf(s), 1e-12f);
    }
    __syncthreads();

    // per-thread landmark columns
    int   lm_r[4];
    float elm_r[4];
    #pragma unroll
    for (int ni = 0; ni < 4; ni++) {
        int r = wv * 64 + ni * 16 + ln;
        lm_r[ni]  = lmtab[r];
        elm_r[ni] = elmtab[r];
    }

    // --- polynomial + mask + decay; row-sum reduce ---
    #pragma unroll
    for (int mi = 0; mi < 4; mi++) {
        #pragma unroll
        for (int reg = 0; reg < 4; reg++) {
            int row = mi * 16 + quad * 4 + reg;
            int t = t0 + row;
            float rn = rnormp[row];
            float e_t = expf(-a_td * (float)t * (1.0f / 4096.0f));
            float s = 0.f;
            #pragma unroll
            for (int ni = 0; ni < 4; ni++) {
                float phi = 0.f;
                if (lm_r[ni] < t) {
                    float c  = acc[mi][ni][reg] * rn;
                    float c2 = c * c;
                    float P1 = 0.5f * (1.f + c);
                    float P2 = 0.5f * (3.f * c2 - 1.f);
                    float P3 = 0.5f * (5.f * c2 * c - 3.f * c);
                    float p  = al0 * P1 + al1 * P2 + al2 * P3;
                    phi = p * e_t * elm_r[ni];
                }
                acc[mi][ni][reg] = phi;
                s += phi;
            }
            #pragma unroll
            for (int off = 1; off < 16; off <<= 1) s += __shfl_xor(s, off, 64);
            if (ln == 0) rspart[wv * TM + row] = s;
        }
    }
    __syncthreads();
    if (tid < TM) {
        float rs = rspart[0 * TM + tid] + rspart[1 * TM + tid]
                 + rspart[2 * TM + tid] + rspart[3 * TM + tid];
        rinvp[tid] = 1.0f / fmaxf(rs, 1e-6f);
    }
    __syncthreads();

    // --- store Phi + ones column ---
    float* ob = out + ((size_t)b * T_DIM + t0) * 257;
    #pragma unroll
    for (int mi = 0; mi < 4; mi++) {
        #pragma unroll
        for (int reg = 0; reg < 4; reg++) {
            int row = mi * 16 + quad * 4 + reg;
            float inv = rinvp[row];
            #pragma unroll
            for (int ni = 0; ni < 4; ni++) {
                int r = wv * 64 + ni * 16 + ln;
                ob[(size_t)row * 257 + r] = acc[mi][ni][reg] * inv;
            }
        }
    }
    if (tid < TM) ob[(size_t)tid * 257 + 256] = 1.0f;
}

extern "C" void kernel_launch(void* const* d_in, const int* in_sizes, int n_in,
                              void* d_out, int out_size, void* d_ws, size_t ws_size,
                              hipStream_t stream) {
    const float* z  = (const float*)d_in[0];
    const float* gw = (const float*)d_in[1];
    const float* ta = (const float*)d_in[2];
    float* out = (float*)d_out;
    __bf16* Khi = (__bf16*)d_ws;                                               // 4 MiB
    __bf16* Klo = (__bf16*)((char*)d_ws + (size_t)B_DIM * R_DIM * D_DIM * 2);  // +4 MiB

    nystrom_prep_kernel<<<dim3(B_DIM * R_DIM), 64, 0, stream>>>(z, Khi, Klo);
    nystrom_main_kernel<<<dim3(T_DIM / TM, B_DIM), 256, 0, stream>>>(z, Khi, Klo, gw, ta, out);
}